// Round 4
// baseline (792.269 us; speedup 1.0000x reference)
//
#include <hip/hip_runtime.h>

// ---------- types ----------
typedef short short8 __attribute__((ext_vector_type(8)));   // 8 bf16 as i16
typedef float f32x4 __attribute__((ext_vector_type(4)));

#define GLOBAL_AS __attribute__((address_space(1)))
#define LDS_AS    __attribute__((address_space(3)))

__device__ __forceinline__ unsigned short f2bf(float f) {
    unsigned u = __builtin_bit_cast(unsigned, f);
    u += 0x7fffu + ((u >> 16) & 1u);          // round-to-nearest-even
    return (unsigned short)(u >> 16);
}

// ---------- convert kernels (memory-bound, vectorized) ----------
__global__ __launch_bounds__(256) void k_idx2bf(const int* __restrict__ idx,
                                                const float* __restrict__ cb,
                                                ushort* __restrict__ out, int n4) {
    int i = blockIdx.x * 256 + threadIdx.x;
    if (i >= n4) return;
    int4 v = reinterpret_cast<const int4*>(idx)[i];
    ushort4 o;
    o.x = f2bf(cb[v.x]); o.y = f2bf(cb[v.y]);
    o.z = f2bf(cb[v.z]); o.w = f2bf(cb[v.w]);
    reinterpret_cast<ushort4*>(out)[i] = o;
}

__global__ __launch_bounds__(256) void k_f2bf(const float* __restrict__ in,
                                              ushort* __restrict__ out, int n4) {
    int i = blockIdx.x * 256 + threadIdx.x;
    if (i >= n4) return;
    float4 v = reinterpret_cast<const float4*>(in)[i];
    ushort4 o;
    o.x = f2bf(v.x); o.y = f2bf(v.y); o.z = f2bf(v.z); o.w = f2bf(v.w);
    reinterpret_cast<ushort4*>(out)[i] = o;
}

// ---------- 256x256 pipelined bf16 gemm_bt: C[M,N] = A[M,K]*B[N,K]^T ----------
// 512 thr = 8 waves (2M x 4N), per-wave out 128x64, BK=64, 2 K-tile LDS dbuf.
// Each operand fragment read from LDS ONCE per K-tile into persistent regs
// (A0/A1 8 frags each, B0/B1 4 each); reads issued one phase ahead of use so
// LDS service overlaps MFMA. All staging for tile t+1 happens during tile t
// into the OTHER buffer (no same-buffer staging). 4 quadrant phases/K-tile,
// 3 barriers, counted vmcnt fences (6/6/-/4). Per-thread VMEM stack per tile:
// ph1 +AE,BE(t+1)[4]; ph2 +BL(t+1)[2]; ph3 +AL(t+1)[2]; fences complete
// exactly the region the following ds_reads need (2 instrs per region).
// Swizzle (verified 0 conflicts): linear LDS dest + pre-swizzled global col
// (slot s of row r holds logical slot s^(r&7)) + XOR'd ds_read address.

#define CH_AE(j) ((((j) & 8) << 1) | ((j) & 7))
#define CH_AL(j) (CH_AE(j) + 8)
#define CH_BE(j) ((((j) & 12) << 1) | ((j) & 3))
#define CH_BL(j) (CH_BE(j) + 4)

#define STAGE2(G, LDSBASE, KB, CF) do {                                         \
    const int c0_ = CF(2 * w), c1_ = CF(2 * w + 1);                             \
    __builtin_amdgcn_global_load_lds(                                           \
        (const GLOBAL_AS void*)((G) + (size_t)(c0_ * 8 + srow8) * 4096 + (KB) + scol), \
        (LDS_AS void*)((LDSBASE) + c0_ * 512), 16, 0, 0);                       \
    __builtin_amdgcn_global_load_lds(                                           \
        (const GLOBAL_AS void*)((G) + (size_t)(c1_ * 8 + srow8) * 4096 + (KB) + scol), \
        (LDS_AS void*)((LDSBASE) + c1_ * 512), 16, 0, 0);                       \
} while (0)

#define FENCE_BAR(N) do {                                                       \
    asm volatile("s_waitcnt vmcnt(" #N ")" ::: "memory");                       \
    __builtin_amdgcn_s_barrier();                                               \
    asm volatile("" ::: "memory");                                              \
} while (0)

#define READ_A(DST, BASE, MH) do {                                              \
    _Pragma("unroll")                                                           \
    for (int k2 = 0; k2 < 2; ++k2)                                              \
        _Pragma("unroll")                                                       \
        for (int mi = 0; mi < 4; ++mi) {                                        \
            const int lb = (arow + (MH) * 64 + mi * 16) * 128 + k2 * 64 + fkb;  \
            DST[k2][mi] = *reinterpret_cast<const short8*>((const char*)(BASE) + (lb ^ swb)); \
        }                                                                       \
} while (0)

#define READ_B(DST, BASE, NH) do {                                              \
    _Pragma("unroll")                                                           \
    for (int k2 = 0; k2 < 2; ++k2)                                              \
        _Pragma("unroll")                                                       \
        for (int ni = 0; ni < 2; ++ni) {                                        \
            const int lb = (brow + (NH) * 32 + ni * 16) * 128 + k2 * 64 + fkb;  \
            DST[k2][ni] = *reinterpret_cast<const short8*>((const char*)(BASE) + (lb ^ swb)); \
        }                                                                       \
} while (0)

#define MFMA_Q(MH, NH, AF, BF) do {                                             \
    __builtin_amdgcn_sched_barrier(0);                                          \
    __builtin_amdgcn_s_setprio(1);                                              \
    _Pragma("unroll")                                                           \
    for (int k2 = 0; k2 < 2; ++k2)                                              \
        _Pragma("unroll")                                                       \
        for (int mi = 0; mi < 4; ++mi)                                          \
            _Pragma("unroll")                                                   \
            for (int ni = 0; ni < 2; ++ni)                                      \
                acc[(MH) * 4 + mi][(NH) * 2 + ni] =                             \
                    __builtin_amdgcn_mfma_f32_16x16x32_bf16(                    \
                        AF[k2][mi], BF[k2][ni], acc[(MH) * 4 + mi][(NH) * 2 + ni], 0, 0, 0); \
    __builtin_amdgcn_s_setprio(0);                                              \
    __builtin_amdgcn_sched_barrier(0);                                          \
} while (0)

// EPI=0: C=bf16, val = acc * extra[row]; EPI=1: C=f32, val = acc + extra[col]
template <int EPI>
__global__ __launch_bounds__(512, 2) void gemm256(const ushort* __restrict__ A,
                                                  const ushort* __restrict__ B,
                                                  void* __restrict__ C,
                                                  const float* __restrict__ extra) {
    constexpr int K = 4096, N = 4096, NT = K / 64;
    __shared__ ushort sA[2][256 * 64];
    __shared__ ushort sB[2][256 * 64];

    const int tid  = threadIdx.x;
    const int w    = tid >> 6;
    const int lane = tid & 63;
    const int wm = w >> 2, wn = w & 3;

    // XCD-aware swizzle (nwg % 8 == 0 for both grids)
    const int nwg = gridDim.x;
    const int sw  = ((int)blockIdx.x & 7) * (nwg >> 3) + ((int)blockIdx.x >> 3);
    const int m0 = (sw >> 4) * 256;      // 16 tiles per N-row (N=4096)
    const int n0 = (sw & 15) * 256;

    const ushort* gA = A + (size_t)m0 * K;
    const ushort* gB = B + (size_t)n0 * K;

    // staging lane geometry: dest = chunk*1024B + lane*16B (linear);
    // global column pre-swizzled: slot (lane&7) of row (lane>>3 mod 8) holds
    // logical slot (lane&7)^(lane>>3)
    const int srow8 = lane >> 3;
    const int scol  = (((lane & 7) ^ (lane >> 3)) * 8);   // ushorts

    // fragment geometry (16x16x32: row=lane&15, k=(lane>>4)*8)
    const int fr   = lane & 15;
    const int fkb  = ((lane >> 4) & 3) * 16;          // byte offset along K
    const int swb  = (fr & 7) << 4;                   // read-side slot XOR
    const int arow = wm * 128 + fr;
    const int brow = wn * 64 + fr;

    f32x4 acc[8][4];
#pragma unroll
    for (int i = 0; i < 8; ++i)
#pragma unroll
        for (int j = 0; j < 4; ++j) acc[i][j] = (f32x4){0.f, 0.f, 0.f, 0.f};

    short8 a0[2][4], a1[2][4], b0f[2][2], b1f[2][2];

    // ---- prologue: stage tile0 (AE,BE,BL,AL order = steady-state stack) ----
    STAGE2(gA, sA[0], 0, CH_AE); STAGE2(gB, sB[0], 0, CH_BE);
    STAGE2(gB, sB[0], 0, CH_BL); STAGE2(gA, sA[0], 0, CH_AL);
    FENCE_BAR(4);                       // AE0,BE0 complete; [BL0,AL0] in flight
    READ_A(a0, sA[0], 0);
    READ_B(b0f, sB[0], 0);

    for (int t = 0; t < NT - 1; ++t) {
        const int cur = t & 1, nx = cur ^ 1;
        const int kb1 = (t + 1) * 64;
        // ph1: Q(0,0); prefetch reads B1(t); stage AE,BE(t+1)
        STAGE2(gA, sA[nx], kb1, CH_AE); STAGE2(gB, sB[nx], kb1, CH_BE);
        FENCE_BAR(6);                   // BL(t) complete -> B-late readable
        READ_B(b1f, sB[cur], 1);
        MFMA_Q(0, 0, a0, b0f);
        // ph2: Q(0,1); prefetch reads A1(t); stage BL(t+1)
        STAGE2(gB, sB[nx], kb1, CH_BL);
        FENCE_BAR(6);                   // AL(t) complete -> A-late readable
        READ_A(a1, sA[cur], 1);
        MFMA_Q(0, 1, a0, b1f);
        // ph3: Q(1,0); stage AL(t+1); no fence/barrier needed
        STAGE2(gA, sA[nx], kb1, CH_AL);
        MFMA_Q(1, 0, a1, b0f);
        // ph4: Q(1,1); prefetch reads A0,B0 of tile t+1 from next buffer
        FENCE_BAR(4);                   // AE,BE(t+1) complete
        READ_A(a0, sA[nx], 0);
        READ_B(b0f, sB[nx], 0);
        MFMA_Q(1, 1, a1, b1f);
    }
    {   // ---- tail tile t = NT-1 (no staging) ----
        const int cur = (NT - 1) & 1;
        FENCE_BAR(2);                   // BL(NT-1) complete
        READ_B(b1f, sB[cur], 1);
        MFMA_Q(0, 0, a0, b0f);
        FENCE_BAR(0);                   // AL(NT-1) complete
        READ_A(a1, sA[cur], 1);
        MFMA_Q(0, 1, a0, b1f);
        MFMA_Q(1, 0, a1, b0f);
        MFMA_Q(1, 1, a1, b1f);
    }

    // ---- epilogue: C/D layout col=lane&15, row=(lane>>4)*4+reg ----
    const int rb = m0 + wm * 128 + ((lane >> 4) * 4);
    const int cb = n0 + wn * 64 + (lane & 15);
    if (EPI == 0) {
        ushort* Cw = (ushort*)C;
#pragma unroll
        for (int mi = 0; mi < 8; ++mi) {
#pragma unroll
            for (int r = 0; r < 4; ++r) {
                const int row = rb + mi * 16 + r;
                const float s = extra[row];
#pragma unroll
                for (int ni = 0; ni < 4; ++ni)
                    Cw[(size_t)row * N + cb + ni * 16] = f2bf(acc[mi][ni][r] * s);
            }
        }
    } else {
        float* Cf = (float*)C;
#pragma unroll
        for (int ni = 0; ni < 4; ++ni) {
            const float b = extra[cb + ni * 16];
#pragma unroll
            for (int mi = 0; mi < 8; ++mi) {
#pragma unroll
                for (int r = 0; r < 4; ++r) {
                    const int row = rb + mi * 16 + r;
                    Cf[(size_t)row * N + cb + ni * 16] = acc[mi][ni][r] + b;
                }
            }
        }
    }
}

// ---------- launch ----------
extern "C" void kernel_launch(void* const* d_in, const int* in_sizes, int n_in,
                              void* d_out, int out_size, void* d_ws, size_t ws_size,
                              hipStream_t stream) {
    const float* x     = (const float*)d_in[0];   // (4,2048,4096) f32
    const int*   widx  = (const int*)  d_in[1];   // (4096,4096) i32
    const float* wscal = (const float*)d_in[2];   // (4096,)
    const float* bias  = (const float*)d_in[3];   // (4096,)
    const float* rot   = (const float*)d_in[4];   // (4096,4096) f32
    const float* cb    = (const float*)d_in[5];   // (16,)
    float* out = (float*)d_out;                   // (4,2048,4096) f32

    constexpr size_t IN_F = 4096, OUT_F = 4096, MTOK = 8192;
    char* ws = (char*)d_ws;
    ushort* wq   = (ushort*)(ws);                 // 32 MiB: codebook[idx] bf16
    ushort* rbuf = (ushort*)(ws + 33554432);      // 32 MiB: rotation bf16
    ushort* xb   = (ushort*)(ws + 67108864);      // 64 MiB: x bf16
    ushort* wb   = (ushort*)(ws + 134217728);     // 32 MiB: dequantized W bf16
    (void)ws_size; (void)in_sizes; (void)n_in; (void)out_size;

    // converts (memory-bound)
    {
        int n4 = (int)(OUT_F * IN_F / 4);
        k_idx2bf<<<n4 / 256, 256, 0, stream>>>(widx, cb, wq, n4);
        k_f2bf<<<n4 / 256, 256, 0, stream>>>(rot, rbuf, n4);
        int n4x = (int)(MTOK * IN_F / 4);
        k_f2bf<<<n4x / 256, 256, 0, stream>>>(x, xb, n4x);
    }

    // GEMM A: W[o,j] = scale[o] * sum_i Wq[o,i] R[j,i]   (M=4096 -> 256 wgs)
    gemm256<0><<<dim3(256), 512, 0, stream>>>(wq, rbuf, (void*)wb, wscal);

    // GEMM B: out[m,o] = sum_j x[m,j] W[o,j] + bias[o]   (M=8192 -> 512 wgs)
    gemm256<1><<<dim3(512), 512, 0, stream>>>(xb, wb, (void*)out, bias);
}

// Round 6
// 509.087 us; speedup vs baseline: 1.5563x; 1.5563x over previous
//
#include <hip/hip_runtime.h>

// ---------- types ----------
typedef short short8 __attribute__((ext_vector_type(8)));   // 8 bf16 as i16
typedef float f32x4 __attribute__((ext_vector_type(4)));

#define GLOBAL_AS __attribute__((address_space(1)))
#define LDS_AS    __attribute__((address_space(3)))

__device__ __forceinline__ unsigned short f2bf(float f) {
    unsigned u = __builtin_bit_cast(unsigned, f);
    u += 0x7fffu + ((u >> 16) & 1u);          // round-to-nearest-even
    return (unsigned short)(u >> 16);
}

// ---------- convert kernels (memory-bound, vectorized) ----------
__global__ __launch_bounds__(256) void k_idx2bf(const int* __restrict__ idx,
                                                const float* __restrict__ cb,
                                                ushort* __restrict__ out, int n4) {
    int i = blockIdx.x * 256 + threadIdx.x;
    if (i >= n4) return;
    int4 v = reinterpret_cast<const int4*>(idx)[i];
    ushort4 o;
    o.x = f2bf(cb[v.x]); o.y = f2bf(cb[v.y]);
    o.z = f2bf(cb[v.z]); o.w = f2bf(cb[v.w]);
    reinterpret_cast<ushort4*>(out)[i] = o;
}

__global__ __launch_bounds__(256) void k_f2bf(const float* __restrict__ in,
                                              ushort* __restrict__ out, int n4) {
    int i = blockIdx.x * 256 + threadIdx.x;
    if (i >= n4) return;
    float4 v = reinterpret_cast<const float4*>(in)[i];
    ushort4 o;
    o.x = f2bf(v.x); o.y = f2bf(v.y); o.z = f2bf(v.z); o.w = f2bf(v.w);
    reinterpret_cast<ushort4*>(out)[i] = o;
}

// ---------- 256x256 m201-template bf16 gemm_bt: C = A[M,K]*B[N,K]^T --------
// 512 thr = 8 waves (2M x 4N), per-wave 128x64 out, BK=64, 2 K-tile LDS dbuf.
// Per K-tile: 4 phases, each = {ds_reads for this quadrant (12/4/8/0, each
// frag once) || stage 1 half-tile (2 gload_lds) -> barrier -> lgkmcnt(0) ->
// setprio(1) -> 16 MFMA -> setprio(0) -> [ph4: vmcnt fence] -> barrier}.
// Stage slots (tile t, cur=t&1): ph1 AL(t+1)->buf[cur^1] (region last read
// ph3 of t-1); ph2 AE(t+2)->buf[cur] (read ph1); ph3 BE(t+2)->buf[cur]
// (read ph1); ph4 BL(t+2)->buf[cur] (read ph2). Each phase's lgkmcnt(0) +
// end-barrier guarantees reads completed before next phase's writes land.
// ph4 fence vmcnt(6) leaves exactly {AE,BE,BL}(t+2) in flight -> tile t+1
// fully resident before its ph1. Prefetch depth ~7 phases > HBM latency.
// Swizzle (0 conflicts, verified r3): linear LDS dest + pre-swizzled global
// col (slot s of row r holds s^(r&7)) + XOR'd ds_read address.

#define CH_AE(j) ((((j) & 8) << 1) | ((j) & 7))
#define CH_AL(j) (CH_AE(j) + 8)
#define CH_BE(j) ((((j) & 12) << 1) | ((j) & 3))
#define CH_BL(j) (CH_BE(j) + 4)

#define STAGE2(G, LDSBASE, KB, CF) do {                                         \
    const int c0_ = CF(2 * w);                                                  \
    const int c1_ = CF(2 * w + 1);                                              \
    __builtin_amdgcn_global_load_lds(                                           \
        (const GLOBAL_AS void*)((G) + (size_t)(c0_ * 8 + srow8) * 4096 + (KB) + scol), \
        (LDS_AS void*)((LDSBASE) + c0_ * 512), 16, 0, 0);                       \
    __builtin_amdgcn_global_load_lds(                                           \
        (const GLOBAL_AS void*)((G) + (size_t)(c1_ * 8 + srow8) * 4096 + (KB) + scol), \
        (LDS_AS void*)((LDSBASE) + c1_ * 512), 16, 0, 0);                       \
} while (0)

#define READ_A(DST, BASE, MH) do {                                              \
    _Pragma("unroll")                                                           \
    for (int k2 = 0; k2 < 2; ++k2)                                              \
        _Pragma("unroll")                                                       \
        for (int mi = 0; mi < 4; ++mi) {                                        \
            const int lb = (arow + (MH) * 64 + mi * 16) * 128 + k2 * 64 + fkb;  \
            DST[k2][mi] = *reinterpret_cast<const short8*>((const char*)(BASE) + (lb ^ swb)); \
        }                                                                       \
} while (0)

#define READ_B(DST, BASE, NH) do {                                              \
    _Pragma("unroll")                                                           \
    for (int k2 = 0; k2 < 2; ++k2)                                              \
        _Pragma("unroll")                                                       \
        for (int ni = 0; ni < 2; ++ni) {                                        \
            const int lb = (brow + (NH) * 32 + ni * 16) * 128 + k2 * 64 + fkb;  \
            DST[k2][ni] = *reinterpret_cast<const short8*>((const char*)(BASE) + (lb ^ swb)); \
        }                                                                       \
} while (0)

#define MFMA16(MH, NH, AF, BF)                                                  \
    _Pragma("unroll")                                                           \
    for (int k2 = 0; k2 < 2; ++k2)                                              \
        _Pragma("unroll")                                                       \
        for (int mi = 0; mi < 4; ++mi)                                          \
            _Pragma("unroll")                                                   \
            for (int ni = 0; ni < 2; ++ni)                                      \
                acc[(MH) * 4 + mi][(NH) * 2 + ni] =                             \
                    __builtin_amdgcn_mfma_f32_16x16x32_bf16(                    \
                        AF[k2][mi], BF[k2][ni], acc[(MH) * 4 + mi][(NH) * 2 + ni], 0, 0, 0)

#define PH_MID                                                                  \
    asm volatile("" ::: "memory");                                              \
    __builtin_amdgcn_s_barrier();                                               \
    asm volatile("s_waitcnt lgkmcnt(0)" ::: "memory");                          \
    __builtin_amdgcn_s_setprio(1)

#define PH_END                                                                  \
    __builtin_amdgcn_s_setprio(0);                                              \
    asm volatile("" ::: "memory");                                              \
    __builtin_amdgcn_s_barrier();                                               \
    asm volatile("" ::: "memory")

// phases: reads + stage(__VA_ARGS__) -> barrier -> lgkm(0) -> MFMA -> barrier
#define PH1(At, Bt, ...) do {                                                   \
    READ_A(aF, At, 0); READ_B(b0f, Bt, 0);                                      \
    __VA_ARGS__;                                                                \
    PH_MID; MFMA16(0, 0, aF, b0f); PH_END;                                      \
} while (0)

#define PH2(Bt, ...) do {                                                       \
    READ_B(b1f, Bt, 1);                                                         \
    __VA_ARGS__;                                                                \
    PH_MID; MFMA16(0, 1, aF, b1f); PH_END;                                      \
} while (0)

#define PH3(At, ...) do {                                                       \
    READ_A(aF, At, 1);                                                          \
    __VA_ARGS__;                                                                \
    PH_MID; MFMA16(1, 0, aF, b0f); PH_END;                                      \
} while (0)

#define PH4(FENCEN, ...) do {                                                   \
    __VA_ARGS__;                                                                \
    PH_MID; MFMA16(1, 1, aF, b1f);                                              \
    __builtin_amdgcn_s_setprio(0);                                              \
    asm volatile("s_waitcnt vmcnt(" #FENCEN ")" ::: "memory");                  \
    __builtin_amdgcn_s_barrier();                                               \
    asm volatile("" ::: "memory");                                              \
} while (0)

#define PH4NF(...) do {                                                         \
    __VA_ARGS__;                                                                \
    PH_MID; MFMA16(1, 1, aF, b1f); PH_END;                                      \
} while (0)

// EPI=0: C=bf16, val = acc * extra[row]; EPI=1: C=f32, val = acc + extra[col]
template <int EPI>
__global__ __launch_bounds__(512, 2) void gemm256(const ushort* __restrict__ A,
                                                  const ushort* __restrict__ B,
                                                  void* __restrict__ C,
                                                  const float* __restrict__ extra) {
    constexpr int K = 4096, N = 4096, NT = K / 64;
    __shared__ ushort sA[2][256 * 64];
    __shared__ ushort sB[2][256 * 64];

    const int tid  = threadIdx.x;
    const int w    = tid >> 6;
    const int lane = tid & 63;
    const int wm = w >> 2, wn = w & 3;

    // XCD-aware swizzle (nwg % 8 == 0 for both grids)
    const int nwg = gridDim.x;
    const int sw  = ((int)blockIdx.x & 7) * (nwg >> 3) + ((int)blockIdx.x >> 3);
    const int m0 = (sw >> 4) * 256;      // 16 tiles per N-row (N=4096)
    const int n0 = (sw & 15) * 256;

    const ushort* gA = A + (size_t)m0 * K;
    const ushort* gB = B + (size_t)n0 * K;

    // staging lane geometry: dest = chunk*1024B + lane*16B (linear);
    // global column pre-swizzled: slot (lane&7) of row (lane>>3 mod 8)
    // holds logical slot (lane&7)^(lane>>3)
    const int srow8 = lane >> 3;
    const int scol  = (((lane & 7) ^ (lane >> 3)) * 8);   // ushorts

    // fragment geometry (16x16x32: row=lane&15, k=(lane>>4)*8)
    const int fr   = lane & 15;
    const int fkb  = ((lane >> 4) & 3) * 16;          // byte offset along K
    const int swb  = (fr & 7) << 4;                   // read-side slot XOR
    const int arow = wm * 128 + fr;
    const int brow = wn * 64 + fr;

    f32x4 acc[8][4];
#pragma unroll
    for (int i = 0; i < 8; ++i)
#pragma unroll
        for (int j = 0; j < 4; ++j) acc[i][j] = (f32x4){0.f, 0.f, 0.f, 0.f};

    short8 aF[2][4], b0f[2][2], b1f[2][2];

    // ---- prologue: tile0 all (8 loads) + tile1 AE,BE,BL (6 loads) ----
    STAGE2(gA, sA[0], 0, CH_AE); STAGE2(gB, sB[0], 0, CH_BE);
    STAGE2(gB, sB[0], 0, CH_BL); STAGE2(gA, sA[0], 0, CH_AL);
    STAGE2(gA, sA[1], 64, CH_AE); STAGE2(gB, sB[1], 64, CH_BE);
    STAGE2(gB, sB[1], 64, CH_BL);
    asm volatile("s_waitcnt vmcnt(6)" ::: "memory");   // tile0 resident
    __builtin_amdgcn_s_barrier();
    asm volatile("" ::: "memory");

    for (int t = 0; t < NT - 2; ++t) {
        const int cur = t & 1;
        const ushort* At = sA[cur];
        const ushort* Bt = sB[cur];
        ushort* An = sA[cur ^ 1];
        ushort* Ac = sA[cur];
        ushort* Bc = sB[cur];
        const int kb1 = (t + 1) * 64, kb2 = (t + 2) * 64;
        PH1(At, Bt, STAGE2(gA, An, kb1, CH_AL));
        PH2(Bt,     STAGE2(gA, Ac, kb2, CH_AE));
        PH3(At,     STAGE2(gB, Bc, kb2, CH_BE));
        PH4(6,      STAGE2(gB, Bc, kb2, CH_BL));
    }
    {   // t = NT-2: only AL(NT-1) stage; drain everything at ph4
        const int cur = (NT - 2) & 1;
        const ushort* At = sA[cur];
        const ushort* Bt = sB[cur];
        ushort* An = sA[cur ^ 1];
        PH1(At, Bt, STAGE2(gA, An, (NT - 1) * 64, CH_AL));
        PH2(Bt, ((void)0));
        PH3(At, ((void)0));
        PH4(0, ((void)0));
    }
    {   // t = NT-1: no staging, no fence
        const int cur = (NT - 1) & 1;
        const ushort* At = sA[cur];
        const ushort* Bt = sB[cur];
        PH1(At, Bt, ((void)0));
        PH2(Bt, ((void)0));
        PH3(At, ((void)0));
        PH4NF(((void)0));
    }

    // ---- epilogue: C/D layout col=lane&15, row=(lane>>4)*4+reg ----
    const int rb = m0 + wm * 128 + ((lane >> 4) * 4);
    const int cb = n0 + wn * 64 + (lane & 15);
    if (EPI == 0) {
        ushort* Cw = (ushort*)C;
#pragma unroll
        for (int mi = 0; mi < 8; ++mi) {
#pragma unroll
            for (int r = 0; r < 4; ++r) {
                const int row = rb + mi * 16 + r;
                const float s = extra[row];
#pragma unroll
                for (int ni = 0; ni < 4; ++ni)
                    Cw[(size_t)row * N + cb + ni * 16] = f2bf(acc[mi][ni][r] * s);
            }
        }
    } else {
        float* Cf = (float*)C;
#pragma unroll
        for (int ni = 0; ni < 4; ++ni) {
            const float b = extra[cb + ni * 16];
#pragma unroll
            for (int mi = 0; mi < 8; ++mi) {
#pragma unroll
                for (int r = 0; r < 4; ++r) {
                    const int row = rb + mi * 16 + r;
                    Cf[(size_t)row * N + cb + ni * 16] = acc[mi][ni][r] + b;
                }
            }
        }
    }
}

// ---------- launch ----------
extern "C" void kernel_launch(void* const* d_in, const int* in_sizes, int n_in,
                              void* d_out, int out_size, void* d_ws, size_t ws_size,
                              hipStream_t stream) {
    const float* x     = (const float*)d_in[0];   // (4,2048,4096) f32
    const int*   widx  = (const int*)  d_in[1];   // (4096,4096) i32
    const float* wscal = (const float*)d_in[2];   // (4096,)
    const float* bias  = (const float*)d_in[3];   // (4096,)
    const float* rot   = (const float*)d_in[4];   // (4096,4096) f32
    const float* cb    = (const float*)d_in[5];   // (16,)
    float* out = (float*)d_out;                   // (4,2048,4096) f32

    constexpr size_t IN_F = 4096, OUT_F = 4096, MTOK = 8192;
    char* ws = (char*)d_ws;
    ushort* wq   = (ushort*)(ws);                 // 32 MiB: codebook[idx] bf16
    ushort* rbuf = (ushort*)(ws + 33554432);      // 32 MiB: rotation bf16
    ushort* xb   = (ushort*)(ws + 67108864);      // 64 MiB: x bf16
    ushort* wb   = (ushort*)(ws + 134217728);     // 32 MiB: dequantized W bf16
    (void)ws_size; (void)in_sizes; (void)n_in; (void)out_size;

    // converts (memory-bound)
    {
        int n4 = (int)(OUT_F * IN_F / 4);
        k_idx2bf<<<n4 / 256, 256, 0, stream>>>(widx, cb, wq, n4);
        k_f2bf<<<n4 / 256, 256, 0, stream>>>(rot, rbuf, n4);
        int n4x = (int)(MTOK * IN_F / 4);
        k_f2bf<<<n4x / 256, 256, 0, stream>>>(x, xb, n4x);
    }

    // GEMM A: W[o,j] = scale[o] * sum_i Wq[o,i] R[j,i]   (M=4096 -> 256 wgs)
    gemm256<0><<<dim3(256), 512, 0, stream>>>(wq, rbuf, (void*)wb, wscal);

    // GEMM B: out[m,o] = sum_j x[m,j] W[o,j] + bias[o]   (M=8192 -> 512 wgs)
    gemm256<1><<<dim3(512), 512, 0, stream>>>(xb, wb, (void*)out, bias);
}